// Round 8
// baseline (148.897 us; speedup 1.0000x reference)
//
#include <hip/hip_runtime.h>

// OverlappingEdgeProcessor: x (4,6,16,512,512) f32.
// Single fused launch, disjoint writers:
//   blocks [0, 2048):    edge-blend blocks — write ONLY the 4-wide strips
//   blocks [2048, ...):  flat nt copy, one float4/thread, SKIPPING strip
//                        locations (stores predicated; row-strip waves are
//                        wave-uniform and skip entirely).
// No write-write hazard: writer sets are exactly complementary.
//
// Edge tables (verified passing R1/R3/R4/R5/R7), delta = ar_idx - er_idx.
// Col strips (faces 0-3, w4=0 'L' / w4=127 'R'), er weights per element:
//   L: {0,1/3,2/3,1}   R: {1,2/3,1/3,0}
// Row strips (faces 0,2,4,5; top h=i / bottom h=508+i), uniform weight
//   t = i/3 (top) or (3-i)/3 (bottom) on er.
// Precedence: row blends win in corners -> col threads on faces 0,2 skip
// h in [0,4) u [508,512).
// Written-by-edge set (== skipped-by-copy set):
//   faces 0,2: (w4==0||w4==127) || (h<4||h>=508)
//   faces 1,3: (w4==0||w4==127)
//   faces 4,5: (h<4||h>=508)

typedef float f4 __attribute__((ext_vector_type(4)));

constexpr int W4 = 128;          // 512 floats / 4
constexpr int PLANE = 512 * W4;  // float4 per (b,f,c) plane = 65536
constexpr int FS = 16 * PLANE;   // face stride = 1048576 float4
constexpr int RO = 508 * W4;     // 508-row offset
constexpr int EDGE_BLOCKS = 2048;

__constant__ int kColDelta[4][2] = {
    {2 * FS + 127, 3 * FS - 127},
    {2 * FS + 127, 1 * FS - 127},
    {-1 * FS + 127, -2 * FS - 127},
    {-3 * FS + 127, -2 * FS - 127}};
__constant__ int kRowDelta[4][2] = {
    {4 * FS, 5 * FS - RO},
    {2 * FS + RO, 3 * FS},
    {-4 * FS, -2 * FS - RO},
    {-5 * FS + RO, -3 * FS}};
__constant__ int kRowFace[4] = {0, 2, 4, 5};

__global__ __launch_bounds__(256) void fused_kernel(
    const f4* __restrict__ in, f4* __restrict__ out) {
  const float inv3 = 1.0f / 3.0f;
  const int bx = blockIdx.x;

  if (bx >= EDGE_BLOCKS) {
    // ---------------- flat copy with strip skip ----------------
    const int i = (bx - EDGE_BLOCKS) * 256 + threadIdx.x;
    const int w4 = i & (W4 - 1);
    const int h = (i >> 7) & 511;
    const int f = (i >> 20) % 6;  // i>>20 = b*6+f (< 24)
    const bool rowFace = (f != 1) & (f != 3);
    const bool rowE = rowFace & ((h < 4) | (h >= 508));
    if (rowE) return;  // wave-uniform: whole strip row owned by edge blocks
    f4 v = __builtin_nontemporal_load(&in[i]);
    const bool colE = (f <= 3) & ((w4 == 0) | (w4 == W4 - 1));
    if (!colE) __builtin_nontemporal_store(v, &out[i]);
    return;
  }

  // ---------------- edge blending ----------------
  const int id = bx * 256 + threadIdx.x;  // [0, 524288)
  if (id < 262144) {
    // column strips
    int cid = id;
    int h = cid & 511; cid >>= 9;
    int c = cid & 15;  cid >>= 4;
    int s = cid & 1;   cid >>= 1;
    int face = cid & 3;  // faces 0..3
    int b = cid >> 2;
    if ((face == 0 || face == 2) && (h < 4 || h >= 508)) return;  // row wins
    int idx = (b * 6 + face) * FS + c * PLANE + h * W4 + (s ? 127 : 0);
    f4 er = in[idx];
    f4 ar = in[idx + kColDelta[face][s]];
    f4 r;
    if (s == 0) {  // left: er w = {0,1/3,2/3,1}
      r = f4{ar.x, er.y * inv3 + ar.y * (2.f * inv3),
             er.z * (2.f * inv3) + ar.z * inv3, er.w};
    } else {       // right: er w = {1,2/3,1/3,0}
      r = f4{er.x, er.y * (2.f * inv3) + ar.y * inv3,
             er.z * inv3 + ar.z * (2.f * inv3), ar.w};
    }
    __builtin_nontemporal_store(r, &out[idx]);
  } else {
    // row strips
    int rid = id - 262144;
    int w4 = rid & 127; rid >>= 7;
    int i2 = rid & 3;   rid >>= 2;
    int c = rid & 15;   rid >>= 4;
    int s = rid & 1;    rid >>= 1;
    int fr = rid & 3;
    int b = rid >> 2;
    int face = kRowFace[fr];
    int h = s ? 508 + i2 : i2;
    int idx = (b * 6 + face) * FS + c * PLANE + h * W4 + w4;
    float t = (s ? (3 - i2) : i2) * inv3;
    float u = 1.0f - t;
    f4 er = in[idx];
    f4 ar = in[idx + kRowDelta[fr][s]];
    f4 r = er * t + ar * u;
    __builtin_nontemporal_store(r, &out[idx]);
  }
}

extern "C" void kernel_launch(void* const* d_in, const int* in_sizes, int n_in,
                              void* d_out, int out_size, void* d_ws,
                              size_t ws_size, hipStream_t stream) {
  const f4* in = (const f4*)d_in[0];
  f4* out = (f4*)d_out;
  int total4 = in_sizes[0] / 4;           // 25,165,824 = 98304 * 256
  int blocks = EDGE_BLOCKS + total4 / 256;  // 2048 edge + 98304 copy
  hipLaunchKernelGGL(fused_kernel, dim3(blocks), dim3(256), 0, stream, in,
                     out);
}

// Round 9
// 145.287 us; speedup vs baseline: 1.0248x; 1.0248x over previous
//
#include <hip/hip_runtime.h>

// OverlappingEdgeProcessor: x (4,6,16,512,512) f32.
// FINAL (revert to R7, best measured: 145.6 us):
//   1) flat nontemporal copy, one float4 per thread, no loop — matches the
//      m13 µbench structure; measured ~5.85 TB/s (93% of 6.29 TB/s ceiling)
//   2) tiny edge kernel overwriting only the 4-wide blend strips (~0.5%).
// R8's fused single-launch variant regressed (+3.3 us): predicate VALU on
// every copy thread costs more than the 24 MB it saves. Keep two dispatches.
//
// Edge tables (verified passing R1/R3/R4/R5/R7/R8), delta = ar_idx - er_idx.
// Col strips (faces 0-3, w4=0 'L' / w4=127 'R'), er weights per element:
//   L: {0,1/3,2/3,1}   R: {1,2/3,1/3,0}
// Row strips (faces 0,2,4,5; top h=i / bottom h=508+i), uniform weight
//   t = i/3 (top) or (3-i)/3 (bottom) on er.
// Precedence: row blends win in corners -> col threads on faces 0,2 skip
// h in [0,4) u [508,512).

typedef float f4 __attribute__((ext_vector_type(4)));

constexpr int W4 = 128;          // 512 floats / 4
constexpr int PLANE = 512 * W4;  // float4 per (b,f,c) plane = 65536
constexpr int FS = 16 * PLANE;   // face stride = 1048576 float4
constexpr int RO = 508 * W4;     // 508-row offset

__constant__ int kColDelta[4][2] = {
    {2 * FS + 127, 3 * FS - 127},
    {2 * FS + 127, 1 * FS - 127},
    {-1 * FS + 127, -2 * FS - 127},
    {-3 * FS + 127, -2 * FS - 127}};
__constant__ int kRowDelta[4][2] = {
    {4 * FS, 5 * FS - RO},
    {2 * FS + RO, 3 * FS},
    {-4 * FS, -2 * FS - RO},
    {-5 * FS + RO, -3 * FS}};
__constant__ int kRowFace[4] = {0, 2, 4, 5};

// One float4 per thread, no loop, nontemporal both ways.
__global__ __launch_bounds__(256) void copy_kernel(
    const f4* __restrict__ in, f4* __restrict__ out) {
  const int i = blockIdx.x * blockDim.x + threadIdx.x;
  f4 v = __builtin_nontemporal_load(&in[i]);
  __builtin_nontemporal_store(v, &out[i]);
}

__global__ __launch_bounds__(256) void edge_fix_kernel(
    const f4* __restrict__ in, f4* __restrict__ out) {
  const int id = blockIdx.x * blockDim.x + threadIdx.x;  // [0, 524288)
  const float inv3 = 1.0f / 3.0f;

  if (id < 262144) {
    // ---- column strips ----
    int cid = id;
    int h = cid & 511; cid >>= 9;
    int c = cid & 15;  cid >>= 4;
    int s = cid & 1;   cid >>= 1;
    int face = cid & 3;           // faces 0..3
    int b = cid >> 2;
    if ((face == 0 || face == 2) && (h < 4 || h >= 508)) return;  // row wins
    int idx = (b * 6 + face) * FS + c * PLANE + h * W4 + (s ? 127 : 0);
    f4 er = in[idx];
    f4 ar = in[idx + kColDelta[face][s]];
    f4 r;
    if (s == 0) {  // left: er w = {0,1/3,2/3,1}
      r = f4{ar.x, er.y * inv3 + ar.y * (2.f * inv3),
             er.z * (2.f * inv3) + ar.z * inv3, er.w};
    } else {       // right: er w = {1,2/3,1/3,0}
      r = f4{er.x, er.y * (2.f * inv3) + ar.y * inv3,
             er.z * inv3 + ar.z * (2.f * inv3), ar.w};
    }
    __builtin_nontemporal_store(r, &out[idx]);
  } else {
    // ---- row strips ----
    int rid = id - 262144;
    int w4 = rid & 127; rid >>= 7;
    int i = rid & 3;    rid >>= 2;
    int c = rid & 15;   rid >>= 4;
    int s = rid & 1;    rid >>= 1;
    int fr = rid & 3;
    int b = rid >> 2;
    int face = kRowFace[fr];
    int h = s ? 508 + i : i;
    int idx = (b * 6 + face) * FS + c * PLANE + h * W4 + w4;
    float t = (s ? (3 - i) : i) * inv3;
    float u = 1.0f - t;
    f4 er = in[idx];
    f4 ar = in[idx + kRowDelta[fr][s]];
    f4 r = er * t + ar * u;
    __builtin_nontemporal_store(r, &out[idx]);
  }
}

extern "C" void kernel_launch(void* const* d_in, const int* in_sizes, int n_in,
                              void* d_out, int out_size, void* d_ws,
                              size_t ws_size, hipStream_t stream) {
  const f4* in = (const f4*)d_in[0];
  f4* out = (f4*)d_out;
  int total4 = in_sizes[0] / 4;  // 25,165,824 = 98304 * 256
  hipLaunchKernelGGL(copy_kernel, dim3(total4 / 256), dim3(256), 0, stream,
                     in, out);
  hipLaunchKernelGGL(edge_fix_kernel, dim3(524288 / 256), dim3(256), 0,
                     stream, in, out);
}